// Round 3
// baseline (1347.791 us; speedup 1.0000x reference)
//
#include <hip/hip_runtime.h>
#include <hip/hip_bf16.h>
#include <cstdint>
#include <cstddef>

using u16 = unsigned short;

#define DEV static __device__ __forceinline__

DEV float bf2f(u16 u) {
  unsigned int x = ((unsigned int)u) << 16;
  float f;
  __builtin_memcpy(&f, &x, 4);
  return f;
}

DEV u16 f2bf(float f) {  // round-to-nearest-even bf16
  unsigned int x;
  __builtin_memcpy(&x, &f, 4);
  unsigned int r = (x + 0x7fffu + ((x >> 16) & 1u)) >> 16;
  return (u16)r;
}

typedef __bf16 bf16x8 __attribute__((ext_vector_type(8)));
typedef float f32x4 __attribute__((ext_vector_type(4)));

DEV f32x4 mfma_bf16(bf16x8 a, bf16x8 b, f32x4 c) {
  return __builtin_amdgcn_mfma_f32_16x16x32_bf16(a, b, c, 0, 0, 0);
}

// async global->LDS, 16B per lane; lds dest is wave-uniform base + lane*16
DEV void async_ld16(const void* g, void* lds) {
  __builtin_amdgcn_global_load_lds((const __attribute__((address_space(1))) void*)g,
                                   (__attribute__((address_space(3))) void*)lds,
                                   16, 0, 0);
}

DEV void hard_barrier() {  // raw barrier, no vmcnt(0) drain; pin scheduler
  __builtin_amdgcn_sched_barrier(0);
  __builtin_amdgcn_s_barrier();
  __builtin_amdgcn_sched_barrier(0);
}

// ---------------------------------------------------------------------------
// fused fp32 -> bf16 (RNE) conversion of all 4 weight tensors
// ---------------------------------------------------------------------------
__global__ __launch_bounds__(256) void k_cvt_all(
    const float* __restrict__ s0, u16* __restrict__ d0, int n0,
    const float* __restrict__ s1, u16* __restrict__ d1, int n1,
    const float* __restrict__ s2, u16* __restrict__ d2, int n2,
    const float* __restrict__ s3, u16* __restrict__ d3, int n3) {
  const int total = n0 + n1 + n2 + n3;
  for (int i = blockIdx.x * 256 + threadIdx.x; i < total; i += gridDim.x * 256) {
    int j = i;
    if (j < n0) { d0[j] = f2bf(s0[j]); continue; }
    j -= n0;
    if (j < n1) { d1[j] = f2bf(s1[j]); continue; }
    j -= n1;
    if (j < n2) { d2[j] = f2bf(s2[j]); continue; }
    j -= n2;
    d3[j] = f2bf(s3[j]);
  }
}

__global__ __launch_bounds__(256) void k_zero(float* __restrict__ p, int n) {
  const int i = blockIdx.x * 256 + threadIdx.x;
  if (i < n) p[i] = 0.f;
}

// ---------------------------------------------------------------------------
// gemm3: C[m,n] = sum_{kk<K} A[m,kk] * W[n, kk mod K0]  (+bias)
// A is the hi|lo concat activation (row length K = 2*K0), W plain bf16 (row
// length K0). 128x256 tile, BK=64, TRIPLE-buffered LDS (144 KB) with counted
// vmcnt: stage tile t+2 at top of iter t -> end-of-iter wait vmcnt(6) is on
// loads issued a full iteration earlier (cover >= HBM latency; never drains
// the fresh stage). Raw s_barrier + sched_barrier fencing. XOR LDS swizzle
// (pre-swizzled global source + swizzled ds_read). setprio around MFMA.
// Requires: M%128==0, N%256==0, K%64==0, K0%64==0, gridDim.x%8==0, K/64>=3.
// ---------------------------------------------------------------------------
template <bool BIAS>
__global__ __launch_bounds__(512, 2) void gemm3(
    const u16* __restrict__ A, const u16* __restrict__ Bw,
    float* __restrict__ Cf, const float* __restrict__ bias,
    int M, int N, int K, int K0, int ldc) {
  __shared__ __align__(16) u16 sA[3 * 128 * 64];  // 48 KB
  __shared__ __align__(16) u16 sB[3 * 256 * 64];  // 96 KB

  const int tid = threadIdx.x;
  const int wave = tid >> 6;
  const int lane = tid & 63;
  const int nwg = gridDim.x;
  // bijective XCD swizzle (nwg % 8 == 0); mb-fastest: 16 m-blocks sharing one
  // B panel land consecutively on the same XCD L2.
  const int w = (blockIdx.x & 7) * (nwg >> 3) + (blockIdx.x >> 3);
  const int mBlocks = M >> 7;
  const int mb = w % mBlocks;
  const int nb = w / mBlocks;
  const int mBase = mb * 128;
  const int nBase = nb * 256;
  const int wm = wave >> 2;  // 0..1 (64-row strip)
  const int wn = wave & 3;   // 0..3 (64-col strip)

  f32x4 acc[4][4];
#pragma unroll
  for (int i = 0; i < 4; ++i)
#pragma unroll
    for (int j = 0; j < 4; ++j) acc[i][j] = f32x4{0.f, 0.f, 0.f, 0.f};

  // staging: per round 512 thr move 8 KB (64 rows x 64k u16). lane l: row
  // +(l>>3), source k-slot (l&7)^(l>>3) (involution); LDS dest stays linear
  // so dest slot s of row r holds source slot s^(r&7).
  const int rl = lane >> 3;
  const int sw = (lane & 7) ^ rl;

  auto stage = [&](int bf, int kt) {
    const int k0 = kt * 64;
    const int ka = k0 + sw * 8;
    const int kb = (k0 >= K0 ? k0 - K0 : k0) + sw * 8;  // virtual W duplication
    u16* dA = sA + bf * (128 * 64);
    u16* dB = sB + bf * (256 * 64);
#pragma unroll
    for (int r = 0; r < 2; ++r) {
      const int row = r * 64 + wave * 8;  // wave-uniform
      async_ld16(A + (size_t)(mBase + row + rl) * K + ka, dA + row * 64);
    }
#pragma unroll
    for (int r = 0; r < 4; ++r) {
      const int row = r * 64 + wave * 8;
      async_ld16(Bw + (size_t)(nBase + row + rl) * K0 + kb, dB + row * 64);
    }
  };

  const int nt = K >> 6;
  stage(0, 0);
  stage(1, 1);
  asm volatile("s_waitcnt vmcnt(6)" ::: "memory");  // tile0 landed
  hard_barrier();

  const int rr = lane & 15;
  const int qh = lane >> 4;  // 16B quarter within 32-k half

  int p = 0, ps = 2;
  for (int t = 0; t < nt; ++t) {
    if (t + 2 < nt) stage(ps, t + 2);  // into buf holding tile t-1 (consumed)
    const u16* bA = sA + p * (128 * 64);
    const u16* bB = sB + p * (256 * 64);
#pragma unroll
    for (int ks = 0; ks < 2; ++ks) {
      const int q = ks * 4 + qh;  // source 16B slot index (0..7)
      bf16x8 aF[4], bF[4];
#pragma unroll
      for (int i = 0; i < 4; ++i) {
        const int ra = wm * 64 + i * 16 + rr;
        aF[i] = *(const bf16x8*)(bA + ra * 64 + ((q ^ (ra & 7)) << 3));
      }
#pragma unroll
      for (int j = 0; j < 4; ++j) {
        const int rb = wn * 64 + j * 16 + rr;
        bF[j] = *(const bf16x8*)(bB + rb * 64 + ((q ^ (rb & 7)) << 3));
      }
      __builtin_amdgcn_s_setprio(1);
#pragma unroll
      for (int i = 0; i < 4; ++i)
#pragma unroll
        for (int j = 0; j < 4; ++j)
          acc[i][j] = mfma_bf16(aF[i], bF[j], acc[i][j]);
      __builtin_amdgcn_s_setprio(0);
    }
    if (t + 1 < nt) {
      // need tile t+1 landed; tile t+2's 6 loads (if staged) may stay in flight
      if (t + 3 <= nt) {
        asm volatile("s_waitcnt vmcnt(6)" ::: "memory");
      } else {
        asm volatile("s_waitcnt vmcnt(0)" ::: "memory");
      }
      hard_barrier();
    }
    p = (p == 2) ? 0 : p + 1;
    ps = (ps == 2) ? 0 : ps + 1;
  }

  // C/D layout: col = lane&15, row = (lane>>4)*4 + reg
  const int r0 = (lane >> 4) * 4;
  const int cn = lane & 15;
#pragma unroll
  for (int i = 0; i < 4; ++i) {
    const int mm = mBase + wm * 64 + i * 16 + r0;
#pragma unroll
    for (int j = 0; j < 4; ++j) {
      const int nn = nBase + wn * 64 + j * 16 + cn;
      float bv = 0.f;
      if constexpr (BIAS) bv = bias[nn];
#pragma unroll
      for (int r = 0; r < 4; ++r)
        Cf[(size_t)(mm + r) * ldc + nn] = acc[i][j][r] + bv;
    }
  }
}

// ---------------------------------------------------------------------------
// gemm_bt (128x128): skinny/odd-N shapes with split-K atomic accumulation.
// A = concat activation (row length K = 2*K0), W plain bf16 (row length K0).
// ---------------------------------------------------------------------------
template <bool BIAS, bool ATOMIC>
__global__ __launch_bounds__(256, 4) void gemm_bt(
    const u16* __restrict__ Ahi, const u16* __restrict__ Bw,
    float* __restrict__ Cf, const float* __restrict__ bias,
    int M, int N, int K, int K0, int ldc, int kChunk) {
  __shared__ __align__(16) u16 sA[128 * 64];
  __shared__ __align__(16) u16 sB[128 * 64];

  const int tid = threadIdx.x;
  const int wave = tid >> 6;
  const int lane = tid & 63;
  const int mBase = blockIdx.y * 128;
  const int nBase = blockIdx.x * 128;
  const int kBeg = blockIdx.z * kChunk;
  const int wm = wave >> 1;
  const int wn = wave & 1;

  f32x4 acc[4][4];
#pragma unroll
  for (int i = 0; i < 4; ++i)
#pragma unroll
    for (int j = 0; j < 4; ++j) acc[i][j] = f32x4{0.f, 0.f, 0.f, 0.f};

  const int rsub = lane >> 3;       // row within 8-row chunk
  const int ksub = (lane & 7) * 8;  // k element offset (8 bf16 = 16B)

  for (int k0 = kBeg; k0 < kBeg + kChunk; k0 += 64) {
    const int kb = (k0 >= K0) ? k0 - K0 : k0;  // virtual W duplication
#pragma unroll
    for (int it = 0; it < 4; ++it) {
      const int chunk = it * 4 + wave;  // wave-uniform
      const int row = chunk * 8 + rsub;
      async_ld16(Ahi + (size_t)(mBase + row) * K + (k0 + ksub), (char*)sA + chunk * 1024);
      int rn = nBase + row;
      if (rn > N - 1) rn = N - 1;  // clamp (junk cols never stored)
      async_ld16(Bw + (size_t)rn * K0 + (kb + ksub), (char*)sB + chunk * 1024);
    }
    __syncthreads();

    const int rr = lane & 15;
    const int q8 = (lane >> 4) * 8;
#pragma unroll
    for (int ks = 0; ks < 64; ks += 32) {
      bf16x8 aH[4], bF[4];
#pragma unroll
      for (int i = 0; i < 4; ++i) {
        aH[i] = *(const bf16x8*)(sA + (wm * 64 + i * 16 + rr) * 64 + ks + q8);
        bF[i] = *(const bf16x8*)(sB + (wn * 64 + i * 16 + rr) * 64 + ks + q8);
      }
#pragma unroll
      for (int i = 0; i < 4; ++i)
#pragma unroll
        for (int j = 0; j < 4; ++j)
          acc[i][j] = mfma_bf16(aH[i], bF[j], acc[i][j]);
    }
    __syncthreads();
  }

  const int r0 = (lane >> 4) * 4;
  const int cn = lane & 15;
#pragma unroll
  for (int i = 0; i < 4; ++i) {
    const int mm = mBase + wm * 64 + i * 16 + r0;
#pragma unroll
    for (int j = 0; j < 4; ++j) {
      const int nn = nBase + wn * 64 + j * 16 + cn;
      if (nn < N) {
        float bv = 0.f;
        if constexpr (BIAS) bv = bias[nn];
#pragma unroll
        for (int r = 0; r < 4; ++r) {
          if constexpr (ATOMIC)
            atomicAdd(&Cf[(size_t)(mm + r) * ldc + nn], acc[i][j][r]);
          else
            Cf[(size_t)(mm + r) * ldc + nn] = acc[i][j][r] + bv;
        }
      }
    }
  }
}

// ---------------------------------------------------------------------------
// Embedding gather (fp32 in) -> concat bf16 hi|lo row (length 1536)
// ---------------------------------------------------------------------------
__global__ __launch_bounds__(256) void k_embed(const int* __restrict__ tok,
                                               const float* __restrict__ emb,
                                               u16* __restrict__ xhl) {
  const int m = blockIdx.x;
  const float* src = emb + (size_t)tok[m] * 768;
  for (int d = threadIdx.x; d < 768; d += 256) {
    const float v = src[d];
    const u16 h = f2bf(v);
    xhl[(size_t)m * 1536 + d] = h;
    xhl[(size_t)m * 1536 + 768 + d] = f2bf(v - bf2f(h));
  }
}

// ---------------------------------------------------------------------------
// Depthwise causal conv (K=4) + bias + silu -> fp32 + concat bf16 hi|lo
// xz: (2048,3072) fp32, xin = cols [0,1536)
// ---------------------------------------------------------------------------
__global__ __launch_bounds__(256) void k_conv(const float* __restrict__ xz,
                                              const float* __restrict__ cw,
                                              const float* __restrict__ cb,
                                              float* __restrict__ xinc,
                                              u16* __restrict__ xihl) {
  const int idx = blockIdx.x * 256 + threadIdx.x;  // 2048*1536
  const int e = idx % 1536;
  const int m = idx / 1536;
  const int t = m & 1023;
  const int b = m >> 10;
  float acc = cb[e];
#pragma unroll
  for (int k = 0; k < 4; ++k) {
    const int tt = t - 3 + k;
    if (tt >= 0) acc += xz[(size_t)((b << 10) + tt) * 3072 + e] * cw[e * 4 + k];
  }
  const float s = acc / (1.f + __expf(-acc));  // silu
  xinc[idx] = s;
  const u16 h = f2bf(s);
  xihl[(size_t)m * 3072 + e] = h;
  xihl[(size_t)m * 3072 + 1536 + e] = f2bf(s - bf2f(h));
}

// ---------------------------------------------------------------------------
// dt_proj (K=48) + bias + softplus -> delta fp32. One block per row m.
// ---------------------------------------------------------------------------
__global__ __launch_bounds__(256) void k_dt(const float* __restrict__ dbc,
                                            const float* __restrict__ dtw,
                                            const float* __restrict__ dtb,
                                            float* __restrict__ delta) {
  const int m = blockIdx.x;
  __shared__ float sd[48];
  if (threadIdx.x < 48) sd[threadIdx.x] = dbc[m * 80 + threadIdx.x];
  __syncthreads();
  for (int e = threadIdx.x; e < 1536; e += 256) {
    float acc = dtb[e];
#pragma unroll
    for (int r = 0; r < 48; ++r) acc += sd[r] * dtw[e * 48 + r];
    const float sp = (acc > 20.f) ? acc : log1pf(__expf(acc));
    delta[m * 1536 + e] = sp;
  }
}

// ---------------------------------------------------------------------------
// Chunk-parallel selective scan (pass1 / combine / pass2).
// ---------------------------------------------------------------------------
#define SCAN_NC 16
#define SCAN_CL 64  // 1024 / SCAN_NC

__global__ __launch_bounds__(256) void k_scan1(
    const float* __restrict__ delta, const float* __restrict__ xinc,
    const float* __restrict__ dbc, const float* __restrict__ alog,
    float* __restrict__ chP, float* __restrict__ chQ) {
  const int b = blockIdx.y;
  const int c = blockIdx.z;
  const int e = blockIdx.x * 16 + (threadIdx.x >> 4);
  const int n = threadIdx.x & 15;
  const float Aen = -__expf(alog[e * 16 + n]);
  const int m0 = (b << 10) + c * SCAN_CL;
  float h = 0.f, P = 1.f;
  float dl = delta[m0 * 1536 + e];
  float xi = xinc[m0 * 1536 + e];
  float Bn = dbc[m0 * 80 + 48 + n];
  for (int t = 0; t < SCAN_CL; ++t) {
    const float dl_c = dl, xi_c = xi, Bn_c = Bn;
    if (t < SCAN_CL - 1) {
      const int m2 = m0 + t + 1;
      dl = delta[m2 * 1536 + e];
      xi = xinc[m2 * 1536 + e];
      Bn = dbc[m2 * 80 + 48 + n];
    }
    const float dA = __expf(dl_c * Aen);
    P *= dA;
    h = dA * h + (dl_c * xi_c) * Bn_c;
  }
  const size_t idx = (((size_t)b * SCAN_NC + c) * 1536 + e) * 16 + n;
  chP[idx] = P;
  chQ[idx] = h;
}

__global__ __launch_bounds__(256) void k_scan_fix(const float* __restrict__ chP,
                                                  const float* __restrict__ chQ,
                                                  float* __restrict__ hst) {
  const int b = blockIdx.y;
  const int e = blockIdx.x * 16 + (threadIdx.x >> 4);
  const int n = threadIdx.x & 15;
  float h = 0.f;
#pragma unroll
  for (int c = 0; c < SCAN_NC; ++c) {
    const size_t idx = (((size_t)b * SCAN_NC + c) * 1536 + e) * 16 + n;
    hst[idx] = h;
    h = chP[idx] * h + chQ[idx];
  }
}

__global__ __launch_bounds__(256) void k_scan2(
    const float* __restrict__ delta, const float* __restrict__ xinc,
    const float* __restrict__ dbc, const float* __restrict__ xz,
    const float* __restrict__ alog, const float* __restrict__ dpar,
    const float* __restrict__ hst, u16* __restrict__ ymhl) {
  const int b = blockIdx.y;
  const int c = blockIdx.z;
  const int e = blockIdx.x * 16 + (threadIdx.x >> 4);
  const int n = threadIdx.x & 15;
  const float Aen = -__expf(alog[e * 16 + n]);
  const float dp = dpar[e];
  const int m0 = (b << 10) + c * SCAN_CL;
  float h = hst[(((size_t)b * SCAN_NC + c) * 1536 + e) * 16 + n];
  float dl = delta[m0 * 1536 + e];
  float xi = xinc[m0 * 1536 + e];
  float Bn = dbc[m0 * 80 + 48 + n];
  float Cn = dbc[m0 * 80 + 64 + n];
  float zz = xz[(size_t)m0 * 3072 + 1536 + e];
  for (int t = 0; t < SCAN_CL; ++t) {
    const float dl_c = dl, xi_c = xi, Bn_c = Bn, Cn_c = Cn, zz_c = zz;
    if (t < SCAN_CL - 1) {  // prefetch next step
      const int m2 = m0 + t + 1;
      dl = delta[m2 * 1536 + e];
      xi = xinc[m2 * 1536 + e];
      Bn = dbc[m2 * 80 + 48 + n];
      Cn = dbc[m2 * 80 + 64 + n];
      zz = xz[(size_t)m2 * 3072 + 1536 + e];
    }
    const float dA = __expf(dl_c * Aen);
    h = dA * h + (dl_c * xi_c) * Bn_c;
    float p = h * Cn_c;
    p += __shfl_xor(p, 1);
    p += __shfl_xor(p, 2);
    p += __shfl_xor(p, 4);
    p += __shfl_xor(p, 8);
    if (n == 0) {
      const float y = p + dp * xi_c;
      const float sz = zz_c / (1.f + __expf(-zz_c));
      const float ym = y * sz;
      const int mt = m0 + t;
      const u16 hh = f2bf(ym);
      ymhl[(size_t)mt * 3072 + e] = hh;
      ymhl[(size_t)mt * 3072 + 1536 + e] = f2bf(ym - bf2f(hh));
    }
  }
}

// ---------------------------------------------------------------------------
// LayerNorm over 768 + affine -> concat bf16 hi|lo row. One block per row.
// ---------------------------------------------------------------------------
__global__ __launch_bounds__(256) void k_ln(const float* __restrict__ g,
                                            const float* __restrict__ w,
                                            const float* __restrict__ bb,
                                            u16* __restrict__ xhl) {
  const int m = blockIdx.x;
  const float* row = g + (size_t)m * 768;
  const int tid = threadIdx.x;
  const float v0 = row[tid], v1 = row[tid + 256], v2 = row[tid + 512];
  float s = v0 + v1 + v2;
#pragma unroll
  for (int o = 32; o > 0; o >>= 1) s += __shfl_xor(s, o);
  __shared__ float red[4];
  if ((tid & 63) == 0) red[tid >> 6] = s;
  __syncthreads();
  const float mu = (red[0] + red[1] + red[2] + red[3]) * (1.f / 768.f);
  const float d0 = v0 - mu, d1 = v1 - mu, d2 = v2 - mu;
  float q = d0 * d0 + d1 * d1 + d2 * d2;
#pragma unroll
  for (int o = 32; o > 0; o >>= 1) q += __shfl_xor(q, o);
  __syncthreads();
  if ((tid & 63) == 0) red[tid >> 6] = q;
  __syncthreads();
  const float var = (red[0] + red[1] + red[2] + red[3]) * (1.f / 768.f);
  const float rs = rsqrtf(var + 1e-5f);
  const float dd[3] = {d0, d1, d2};
#pragma unroll
  for (int i = 0; i < 3; ++i) {
    const int d = tid + i * 256;
    const float y = dd[i] * rs * w[d] + bb[d];
    const u16 h = f2bf(y);
    xhl[(size_t)m * 1536 + d] = h;
    xhl[(size_t)m * 1536 + 768 + d] = f2bf(y - bf2f(h));
  }
}

// ---------------------------------------------------------------------------
extern "C" void kernel_launch(void* const* d_in, const int* in_sizes, int n_in,
                              void* d_out, int out_size, void* d_ws, size_t ws_size,
                              hipStream_t stream) {
  const int* tokens = (const int*)d_in[0];
  const float* embed = (const float*)d_in[1];
  const float* in_w = (const float*)d_in[2];
  const float* conv_w = (const float*)d_in[3];
  const float* conv_b = (const float*)d_in[4];
  const float* xp_w = (const float*)d_in[5];
  const float* dt_w = (const float*)d_in[6];
  const float* dt_b = (const float*)d_in[7];
  const float* A_log = (const float*)d_in[8];
  const float* D_par = (const float*)d_in[9];
  const float* out_w = (const float*)d_in[10];
  const float* ln_w = (const float*)d_in[11];
  const float* ln_b = (const float*)d_in[12];
  const float* head_w = (const float*)d_in[13];
  const float* head_b = (const float*)d_in[14];

  char* p = (char*)d_ws;
  auto alloc = [&](size_t bytes) {
    char* r = p;
    p += (bytes + 255) & ~(size_t)255;
    return r;
  };
  float* xz = (float*)alloc(2048ull * 3072 * 4);     // in_proj out (xin | z)
  float* xinc = (float*)alloc(2048ull * 1536 * 4);   // conv+silu fp32
  u16* xihl = (u16*)alloc(2048ull * 3072 * 2);       // conv+silu hi|lo concat
  float* dbc = (float*)alloc(2048ull * 80 * 4);      // x_proj out
  float* delta = (float*)alloc(2048ull * 1536 * 4);  // softplus(dt_proj)
  u16* ymhl = (u16*)alloc(2048ull * 3072 * 2);       // gated scan out hi|lo
  float* gout = (float*)alloc(2048ull * 768 * 4);    // out_proj (pre-LN)
  u16* xhl = (u16*)alloc(2048ull * 1536 * 2);        // layer input hi|lo
  u16* w_in_h = (u16*)alloc(2ull * 3072 * 768 * 2);  // bf16 weights (plain)
  u16* w_xp_h = (u16*)alloc(2ull * 80 * 1536 * 2);
  u16* w_out_h = (u16*)alloc(2ull * 768 * 1536 * 2);
  u16* w_head_h = (u16*)alloc(32000ull * 768 * 2);
  float* chP = (float*)alloc(2ull * SCAN_NC * 1536 * 16 * 4);  // chunk prod(dA)
  float* chQ = (float*)alloc(2ull * SCAN_NC * 1536 * 16 * 4);  // chunk local h
  float* hst = (float*)alloc(2ull * SCAN_NC * 1536 * 16 * 4);  // chunk h_start

  // weight bf16 pre-pass (one fused kernel)
  k_cvt_all<<<4096, 256, 0, stream>>>(in_w, w_in_h, 2 * 3072 * 768,
                                      xp_w, w_xp_h, 2 * 80 * 1536,
                                      out_w, w_out_h, 2 * 768 * 1536,
                                      head_w, w_head_h, 32000 * 768);

  k_embed<<<2048, 256, 0, stream>>>(tokens, embed, xhl);

  for (int l = 0; l < 2; ++l) {
    // in_proj: M=2048 N=3072 K'=1536 (K0=768) -> gemm3, grid 16*12=192
    gemm3<false><<<192, 512, 0, stream>>>(
        xhl, w_in_h + (size_t)l * 2359296, xz, nullptr, 2048, 3072, 1536, 768, 3072);

    k_conv<<<12288, 256, 0, stream>>>(xz, conv_w + l * 6144, conv_b + l * 1536, xinc, xihl);

    // x_proj: N=80 K'=3072 (K0=1536) -> split-K (12 chunks of 256) atomic
    k_zero<<<640, 256, 0, stream>>>(dbc, 2048 * 80);
    gemm_bt<false, true><<<dim3(1, 16, 12), 256, 0, stream>>>(
        xihl, w_xp_h + (size_t)l * 122880, dbc, nullptr, 2048, 80, 3072, 1536, 80, 256);

    k_dt<<<2048, 256, 0, stream>>>(dbc, dt_w + (size_t)l * 73728, dt_b + l * 1536, delta);

    k_scan1<<<dim3(96, 2, SCAN_NC), 256, 0, stream>>>(
        delta, xinc, dbc, A_log + l * 24576, chP, chQ);
    k_scan_fix<<<dim3(96, 2), 256, 0, stream>>>(chP, chQ, hst);
    k_scan2<<<dim3(96, 2, SCAN_NC), 256, 0, stream>>>(
        delta, xinc, dbc, xz, A_log + l * 24576, D_par + l * 1536, hst, ymhl);

    // out_proj: N=768 K'=3072 (K0=1536) -> split-K (8 chunks of 384) atomic
    k_zero<<<6144, 256, 0, stream>>>(gout, 2048 * 768);
    gemm_bt<false, true><<<dim3(6, 16, 8), 256, 0, stream>>>(
        ymhl, w_out_h + (size_t)l * 1179648, gout, nullptr, 2048, 768, 3072, 1536, 768, 384);

    k_ln<<<2048, 256, 0, stream>>>(gout, ln_w + l * 768, ln_b + l * 768, xhl);
  }

  // head: M=2048 N=32000 K'=1536 (K0=768) -> gemm3, grid 16*125=2000
  gemm3<true><<<2000, 512, 0, stream>>>(
      xhl, w_head_h, (float*)d_out, head_b, 2048, 32000, 1536, 768, 32000);
}

// Round 4
// 1216.354 us; speedup vs baseline: 1.1081x; 1.1081x over previous
//
#include <hip/hip_runtime.h>
#include <hip/hip_bf16.h>
#include <cstdint>
#include <cstddef>

using u16 = unsigned short;

#define DEV static __device__ __forceinline__

DEV float bf2f(u16 u) {
  unsigned int x = ((unsigned int)u) << 16;
  float f;
  __builtin_memcpy(&f, &x, 4);
  return f;
}

DEV u16 f2bf(float f) {  // round-to-nearest-even bf16
  unsigned int x;
  __builtin_memcpy(&x, &f, 4);
  unsigned int r = (x + 0x7fffu + ((x >> 16) & 1u)) >> 16;
  return (u16)r;
}

typedef __bf16 bf16x8 __attribute__((ext_vector_type(8)));
typedef float f32x4 __attribute__((ext_vector_type(4)));
typedef unsigned short u16x4 __attribute__((ext_vector_type(4)));

DEV f32x4 mfma_bf16(bf16x8 a, bf16x8 b, f32x4 c) {
  return __builtin_amdgcn_mfma_f32_16x16x32_bf16(a, b, c, 0, 0, 0);
}

// async global->LDS, 16B per lane; lds dest is wave-uniform base + lane*16
DEV void async_ld16(const void* g, void* lds) {
  __builtin_amdgcn_global_load_lds((const __attribute__((address_space(1))) void*)g,
                                   (__attribute__((address_space(3))) void*)lds,
                                   16, 0, 0);
}

// ---------------------------------------------------------------------------
// fused fp32 -> bf16 (RNE) conversion of all 4 weight tensors, float4-wide
// (all sizes divisible by 4; G13 vectorization)
// ---------------------------------------------------------------------------
__global__ __launch_bounds__(256) void k_cvt_all(
    const float* __restrict__ s0, u16* __restrict__ d0, int n0,
    const float* __restrict__ s1, u16* __restrict__ d1, int n1,
    const float* __restrict__ s2, u16* __restrict__ d2, int n2,
    const float* __restrict__ s3, u16* __restrict__ d3, int n3) {
  const int t0 = n0 >> 2, t1 = n1 >> 2, t2 = n2 >> 2, t3 = n3 >> 2;
  const int total = t0 + t1 + t2 + t3;
  for (int i = blockIdx.x * 256 + threadIdx.x; i < total; i += gridDim.x * 256) {
    int j = i;
    const float* s;
    u16* d;
    if (j < t0) {
      s = s0; d = d0;
    } else {
      j -= t0;
      if (j < t1) {
        s = s1; d = d1;
      } else {
        j -= t1;
        if (j < t2) {
          s = s2; d = d2;
        } else {
          j -= t2;
          s = s3; d = d3;
        }
      }
    }
    const float4 v = *(const float4*)(s + 4 * (size_t)j);
    u16x4 o;
    o.x = f2bf(v.x);
    o.y = f2bf(v.y);
    o.z = f2bf(v.z);
    o.w = f2bf(v.w);
    *(u16x4*)(d + 4 * (size_t)j) = o;
  }
}

// transpose dt_w: [NL][1536][48] -> [NL][48][1536] (coalesced k_dt reads)
__global__ __launch_bounds__(256) void k_dtt(const float* __restrict__ src,
                                             float* __restrict__ dst) {
  const int i = blockIdx.x * 256 + threadIdx.x;  // over 2*48*1536
  if (i < 2 * 48 * 1536) {
    const int l = i / 73728;
    const int j = i % 73728;
    const int r = j / 1536;
    const int e = j % 1536;
    dst[i] = src[l * 73728 + e * 48 + r];
  }
}

__global__ __launch_bounds__(256) void k_zero(float* __restrict__ p, int n) {
  const int i = blockIdx.x * 256 + threadIdx.x;
  if (i < n) p[i] = 0.f;
}

// ---------------------------------------------------------------------------
// gemm4: C[m,n] = sum_{kk<K} A[m,kk] * W[n, kk mod K0]  (+bias)
// A = hi|lo concat activation (row length K = 2*K0), W plain bf16 (row K0).
// 128x128 tile, BK=64, SINGLE-buffer 32 KB LDS -> 4 blocks/CU (TLP covers the
// barrier drain, m114). XOR LDS swizzle both-sides (pre-swizzled global source
// + swizzled ds_read; conflict-free). setprio around MFMA. Bijective XCD
// swizzle, mb-fastest (16 m-blocks share one B panel in L2).
// Requires: M%128==0, N%128==0, K%64==0, K0%64==0, gridDim.x%8==0.
// ---------------------------------------------------------------------------
template <bool BIAS>
__global__ __launch_bounds__(256, 4) void gemm4(
    const u16* __restrict__ A, const u16* __restrict__ Bw,
    float* __restrict__ Cf, const float* __restrict__ bias,
    int M, int N, int K, int K0, int ldc) {
  __shared__ __align__(16) u16 sA[128 * 64];
  __shared__ __align__(16) u16 sB[128 * 64];

  const int tid = threadIdx.x;
  const int wave = tid >> 6;
  const int lane = tid & 63;
  const int nwg = gridDim.x;
  const int w = (blockIdx.x & 7) * (nwg >> 3) + (blockIdx.x >> 3);
  const int mBlocks = M >> 7;
  const int mb = w % mBlocks;
  const int nb = w / mBlocks;
  const int mBase = mb * 128;
  const int nBase = nb * 128;
  const int wm = wave >> 1;
  const int wn = wave & 1;

  f32x4 acc[4][4];
#pragma unroll
  for (int i = 0; i < 4; ++i)
#pragma unroll
    for (int j = 0; j < 4; ++j) acc[i][j] = f32x4{0.f, 0.f, 0.f, 0.f};

  // staging: lane l -> row chunk*8+(l>>3); SOURCE k-slot (l&7)^(l>>3) so that
  // linear LDS dest slot s of row r holds source slot s^(r&7) (rule #21).
  const int rsub = lane >> 3;
  const int ksub = ((lane & 7) ^ rsub) * 8;

  const int rr = lane & 15;
  const int qh = lane >> 4;  // 16B quarter

  for (int k0 = 0; k0 < K; k0 += 64) {
    const int kb = (k0 >= K0 ? k0 - K0 : k0);  // virtual W duplication
#pragma unroll
    for (int it = 0; it < 4; ++it) {
      const int chunk = it * 4 + wave;  // wave-uniform
      const int row = chunk * 8 + rsub;
      async_ld16(A + (size_t)(mBase + row) * K + (k0 + ksub), (char*)sA + chunk * 1024);
      async_ld16(Bw + (size_t)(nBase + row) * K0 + (kb + ksub), (char*)sB + chunk * 1024);
    }
    __syncthreads();

#pragma unroll
    for (int ks = 0; ks < 2; ++ks) {
      const int q = ks * 4 + qh;  // source 16B slot (0..7)
      bf16x8 aF[4], bF[4];
#pragma unroll
      for (int i = 0; i < 4; ++i) {
        const int ra = wm * 64 + i * 16 + rr;
        aF[i] = *(const bf16x8*)(sA + ra * 64 + ((q ^ (ra & 7)) << 3));
        const int rb = wn * 64 + i * 16 + rr;
        bF[i] = *(const bf16x8*)(sB + rb * 64 + ((q ^ (rb & 7)) << 3));
      }
      __builtin_amdgcn_s_setprio(1);
#pragma unroll
      for (int i = 0; i < 4; ++i)
#pragma unroll
        for (int j = 0; j < 4; ++j)
          acc[i][j] = mfma_bf16(aF[i], bF[j], acc[i][j]);
      __builtin_amdgcn_s_setprio(0);
    }
    __syncthreads();
  }

  // C/D layout: col = lane&15, row = (lane>>4)*4 + reg
  const int r0 = (lane >> 4) * 4;
  const int cn = lane & 15;
#pragma unroll
  for (int i = 0; i < 4; ++i) {
    const int mm = mBase + wm * 64 + i * 16 + r0;
#pragma unroll
    for (int j = 0; j < 4; ++j) {
      const int nn = nBase + wn * 64 + j * 16 + cn;
      if (nn < N) {
        float bv = 0.f;
        if constexpr (BIAS) bv = bias[nn];
#pragma unroll
        for (int r = 0; r < 4; ++r)
          Cf[(size_t)(mm + r) * ldc + nn] = acc[i][j][r] + bv;
      }
    }
  }
}

// ---------------------------------------------------------------------------
// gemm_bt (128x128): skinny/odd-N shapes with split-K atomic accumulation.
// A = concat activation (row length K = 2*K0), W plain bf16 (row length K0).
// ---------------------------------------------------------------------------
template <bool BIAS, bool ATOMIC>
__global__ __launch_bounds__(256, 4) void gemm_bt(
    const u16* __restrict__ Ahi, const u16* __restrict__ Bw,
    float* __restrict__ Cf, const float* __restrict__ bias,
    int M, int N, int K, int K0, int ldc, int kChunk) {
  __shared__ __align__(16) u16 sA[128 * 64];
  __shared__ __align__(16) u16 sB[128 * 64];

  const int tid = threadIdx.x;
  const int wave = tid >> 6;
  const int lane = tid & 63;
  const int mBase = blockIdx.y * 128;
  const int nBase = blockIdx.x * 128;
  const int kBeg = blockIdx.z * kChunk;
  const int wm = wave >> 1;
  const int wn = wave & 1;

  f32x4 acc[4][4];
#pragma unroll
  for (int i = 0; i < 4; ++i)
#pragma unroll
    for (int j = 0; j < 4; ++j) acc[i][j] = f32x4{0.f, 0.f, 0.f, 0.f};

  const int rsub = lane >> 3;       // row within 8-row chunk
  const int ksub = (lane & 7) * 8;  // k element offset (8 bf16 = 16B)

  for (int k0 = kBeg; k0 < kBeg + kChunk; k0 += 64) {
    const int kb = (k0 >= K0) ? k0 - K0 : k0;  // virtual W duplication
#pragma unroll
    for (int it = 0; it < 4; ++it) {
      const int chunk = it * 4 + wave;  // wave-uniform
      const int row = chunk * 8 + rsub;
      async_ld16(Ahi + (size_t)(mBase + row) * K + (k0 + ksub), (char*)sA + chunk * 1024);
      int rn = nBase + row;
      if (rn > N - 1) rn = N - 1;  // clamp (junk cols never stored)
      async_ld16(Bw + (size_t)rn * K0 + (kb + ksub), (char*)sB + chunk * 1024);
    }
    __syncthreads();

    const int rr = lane & 15;
    const int q8 = (lane >> 4) * 8;
#pragma unroll
    for (int ks = 0; ks < 64; ks += 32) {
      bf16x8 aH[4], bF[4];
#pragma unroll
      for (int i = 0; i < 4; ++i) {
        aH[i] = *(const bf16x8*)(sA + (wm * 64 + i * 16 + rr) * 64 + ks + q8);
        bF[i] = *(const bf16x8*)(sB + (wn * 64 + i * 16 + rr) * 64 + ks + q8);
      }
#pragma unroll
      for (int i = 0; i < 4; ++i)
#pragma unroll
        for (int j = 0; j < 4; ++j)
          acc[i][j] = mfma_bf16(aH[i], bF[j], acc[i][j]);
    }
    __syncthreads();
  }

  const int r0 = (lane >> 4) * 4;
  const int cn = lane & 15;
#pragma unroll
  for (int i = 0; i < 4; ++i) {
    const int mm = mBase + wm * 64 + i * 16 + r0;
#pragma unroll
    for (int j = 0; j < 4; ++j) {
      const int nn = nBase + wn * 64 + j * 16 + cn;
      if (nn < N) {
        float bv = 0.f;
        if constexpr (BIAS) bv = bias[nn];
#pragma unroll
        for (int r = 0; r < 4; ++r) {
          if constexpr (ATOMIC)
            atomicAdd(&Cf[(size_t)(mm + r) * ldc + nn], acc[i][j][r]);
          else
            Cf[(size_t)(mm + r) * ldc + nn] = acc[i][j][r] + bv;
        }
      }
    }
  }
}

// ---------------------------------------------------------------------------
// Embedding gather (fp32 in) -> concat bf16 hi|lo row (length 1536)
// ---------------------------------------------------------------------------
__global__ __launch_bounds__(256) void k_embed(const int* __restrict__ tok,
                                               const float* __restrict__ emb,
                                               u16* __restrict__ xhl) {
  const int m = blockIdx.x;
  const float* src = emb + (size_t)tok[m] * 768;
  const int d4 = threadIdx.x;  // 192 float4 per row
  if (d4 < 192) {
    const float4 v = *(const float4*)(src + d4 * 4);
    u16x4 h, lo;
    h.x = f2bf(v.x); h.y = f2bf(v.y); h.z = f2bf(v.z); h.w = f2bf(v.w);
    lo.x = f2bf(v.x - bf2f(h.x));
    lo.y = f2bf(v.y - bf2f(h.y));
    lo.z = f2bf(v.z - bf2f(h.z));
    lo.w = f2bf(v.w - bf2f(h.w));
    *(u16x4*)(xhl + (size_t)m * 1536 + d4 * 4) = h;
    *(u16x4*)(xhl + (size_t)m * 1536 + 768 + d4 * 4) = lo;
  }
}

// ---------------------------------------------------------------------------
// Depthwise causal conv (K=4) + bias + silu -> fp32 + concat bf16 hi|lo
// xz: (2048,3072) fp32, xin = cols [0,1536)
// ---------------------------------------------------------------------------
__global__ __launch_bounds__(256) void k_conv(const float* __restrict__ xz,
                                              const float* __restrict__ cw,
                                              const float* __restrict__ cb,
                                              float* __restrict__ xinc,
                                              u16* __restrict__ xihl) {
  const int idx = blockIdx.x * 256 + threadIdx.x;  // 2048*1536
  const int e = idx % 1536;
  const int m = idx / 1536;
  const int t = m & 1023;
  const int b = m >> 10;
  float acc = cb[e];
#pragma unroll
  for (int k = 0; k < 4; ++k) {
    const int tt = t - 3 + k;
    if (tt >= 0) acc += xz[(size_t)((b << 10) + tt) * 3072 + e] * cw[e * 4 + k];
  }
  const float s = acc / (1.f + __expf(-acc));  // silu
  xinc[idx] = s;
  const u16 h = f2bf(s);
  xihl[(size_t)m * 3072 + e] = h;
  xihl[(size_t)m * 3072 + 1536 + e] = f2bf(s - bf2f(h));
}

// ---------------------------------------------------------------------------
// dt_proj (K=48, transposed weights) + bias + softplus -> delta fp32.
// One block per row m; dtwT[r*1536+e] reads are coalesced along e.
// ---------------------------------------------------------------------------
__global__ __launch_bounds__(256) void k_dt(const float* __restrict__ dbc,
                                            const float* __restrict__ dtwT,
                                            const float* __restrict__ dtb,
                                            float* __restrict__ delta) {
  const int m = blockIdx.x;
  __shared__ float sd[48];
  if (threadIdx.x < 48) sd[threadIdx.x] = dbc[m * 80 + threadIdx.x];
  __syncthreads();
  for (int e = threadIdx.x; e < 1536; e += 256) {
    float acc = dtb[e];
#pragma unroll
    for (int r = 0; r < 48; ++r) acc += sd[r] * dtwT[r * 1536 + e];
    const float sp = (acc > 20.f) ? acc : log1pf(__expf(acc));
    delta[m * 1536 + e] = sp;
  }
}

// ---------------------------------------------------------------------------
// Chunk-parallel selective scan (pass1 / combine / pass2).
// ---------------------------------------------------------------------------
#define SCAN_NC 16
#define SCAN_CL 64  // 1024 / SCAN_NC

__global__ __launch_bounds__(256) void k_scan1(
    const float* __restrict__ delta, const float* __restrict__ xinc,
    const float* __restrict__ dbc, const float* __restrict__ alog,
    float* __restrict__ chP, float* __restrict__ chQ) {
  const int b = blockIdx.y;
  const int c = blockIdx.z;
  const int e = blockIdx.x * 16 + (threadIdx.x >> 4);
  const int n = threadIdx.x & 15;
  const float Aen = -__expf(alog[e * 16 + n]);
  const int m0 = (b << 10) + c * SCAN_CL;
  float h = 0.f, P = 1.f;
  float dl = delta[m0 * 1536 + e];
  float xi = xinc[m0 * 1536 + e];
  float Bn = dbc[m0 * 80 + 48 + n];
  for (int t = 0; t < SCAN_CL; ++t) {
    const float dl_c = dl, xi_c = xi, Bn_c = Bn;
    if (t < SCAN_CL - 1) {
      const int m2 = m0 + t + 1;
      dl = delta[m2 * 1536 + e];
      xi = xinc[m2 * 1536 + e];
      Bn = dbc[m2 * 80 + 48 + n];
    }
    const float dA = __expf(dl_c * Aen);
    P *= dA;
    h = dA * h + (dl_c * xi_c) * Bn_c;
  }
  const size_t idx = (((size_t)b * SCAN_NC + c) * 1536 + e) * 16 + n;
  chP[idx] = P;
  chQ[idx] = h;
}

__global__ __launch_bounds__(256) void k_scan_fix(const float* __restrict__ chP,
                                                  const float* __restrict__ chQ,
                                                  float* __restrict__ hst) {
  const int b = blockIdx.y;
  const int e = blockIdx.x * 16 + (threadIdx.x >> 4);
  const int n = threadIdx.x & 15;
  float h = 0.f;
#pragma unroll
  for (int c = 0; c < SCAN_NC; ++c) {
    const size_t idx = (((size_t)b * SCAN_NC + c) * 1536 + e) * 16 + n;
    hst[idx] = h;
    h = chP[idx] * h + chQ[idx];
  }
}

__global__ __launch_bounds__(256) void k_scan2(
    const float* __restrict__ delta, const float* __restrict__ xinc,
    const float* __restrict__ dbc, const float* __restrict__ xz,
    const float* __restrict__ alog, const float* __restrict__ dpar,
    const float* __restrict__ hst, u16* __restrict__ ymhl) {
  const int b = blockIdx.y;
  const int c = blockIdx.z;
  const int e = blockIdx.x * 16 + (threadIdx.x >> 4);
  const int n = threadIdx.x & 15;
  const float Aen = -__expf(alog[e * 16 + n]);
  const float dp = dpar[e];
  const int m0 = (b << 10) + c * SCAN_CL;
  float h = hst[(((size_t)b * SCAN_NC + c) * 1536 + e) * 16 + n];
  float dl = delta[m0 * 1536 + e];
  float xi = xinc[m0 * 1536 + e];
  float Bn = dbc[m0 * 80 + 48 + n];
  float Cn = dbc[m0 * 80 + 64 + n];
  float zz = xz[(size_t)m0 * 3072 + 1536 + e];
  for (int t = 0; t < SCAN_CL; ++t) {
    const float dl_c = dl, xi_c = xi, Bn_c = Bn, Cn_c = Cn, zz_c = zz;
    if (t < SCAN_CL - 1) {  // prefetch next step
      const int m2 = m0 + t + 1;
      dl = delta[m2 * 1536 + e];
      xi = xinc[m2 * 1536 + e];
      Bn = dbc[m2 * 80 + 48 + n];
      Cn = dbc[m2 * 80 + 64 + n];
      zz = xz[(size_t)m2 * 3072 + 1536 + e];
    }
    const float dA = __expf(dl_c * Aen);
    h = dA * h + (dl_c * xi_c) * Bn_c;
    float p = h * Cn_c;
    p += __shfl_xor(p, 1);
    p += __shfl_xor(p, 2);
    p += __shfl_xor(p, 4);
    p += __shfl_xor(p, 8);
    if (n == 0) {
      const float y = p + dp * xi_c;
      const float sz = zz_c / (1.f + __expf(-zz_c));
      const float ym = y * sz;
      const int mt = m0 + t;
      const u16 hh = f2bf(ym);
      ymhl[(size_t)mt * 3072 + e] = hh;
      ymhl[(size_t)mt * 3072 + 1536 + e] = f2bf(ym - bf2f(hh));
    }
  }
}

// ---------------------------------------------------------------------------
// LayerNorm over 768 + affine -> concat bf16 hi|lo row. One block per row.
// ---------------------------------------------------------------------------
__global__ __launch_bounds__(256) void k_ln(const float* __restrict__ g,
                                            const float* __restrict__ w,
                                            const float* __restrict__ bb,
                                            u16* __restrict__ xhl) {
  const int m = blockIdx.x;
  const float* row = g + (size_t)m * 768;
  const int tid = threadIdx.x;
  const float v0 = row[tid], v1 = row[tid + 256], v2 = row[tid + 512];
  float s = v0 + v1 + v2;
#pragma unroll
  for (int o = 32; o > 0; o >>= 1) s += __shfl_xor(s, o);
  __shared__ float red[4];
  if ((tid & 63) == 0) red[tid >> 6] = s;
  __syncthreads();
  const float mu = (red[0] + red[1] + red[2] + red[3]) * (1.f / 768.f);
  const float d0 = v0 - mu, d1 = v1 - mu, d2 = v2 - mu;
  float q = d0 * d0 + d1 * d1 + d2 * d2;
#pragma unroll
  for (int o = 32; o > 0; o >>= 1) q += __shfl_xor(q, o);
  __syncthreads();
  if ((tid & 63) == 0) red[tid >> 6] = q;
  __syncthreads();
  const float var = (red[0] + red[1] + red[2] + red[3]) * (1.f / 768.f);
  const float rs = rsqrtf(var + 1e-5f);
  const float dd[3] = {d0, d1, d2};
#pragma unroll
  for (int i = 0; i < 3; ++i) {
    const int d = tid + i * 256;
    const float y = dd[i] * rs * w[d] + bb[d];
    const u16 h = f2bf(y);
    xhl[(size_t)m * 1536 + d] = h;
    xhl[(size_t)m * 1536 + 768 + d] = f2bf(y - bf2f(h));
  }
}

// ---------------------------------------------------------------------------
extern "C" void kernel_launch(void* const* d_in, const int* in_sizes, int n_in,
                              void* d_out, int out_size, void* d_ws, size_t ws_size,
                              hipStream_t stream) {
  const int* tokens = (const int*)d_in[0];
  const float* embed = (const float*)d_in[1];
  const float* in_w = (const float*)d_in[2];
  const float* conv_w = (const float*)d_in[3];
  const float* conv_b = (const float*)d_in[4];
  const float* xp_w = (const float*)d_in[5];
  const float* dt_w = (const float*)d_in[6];
  const float* dt_b = (const float*)d_in[7];
  const float* A_log = (const float*)d_in[8];
  const float* D_par = (const float*)d_in[9];
  const float* out_w = (const float*)d_in[10];
  const float* ln_w = (const float*)d_in[11];
  const float* ln_b = (const float*)d_in[12];
  const float* head_w = (const float*)d_in[13];
  const float* head_b = (const float*)d_in[14];

  char* p = (char*)d_ws;
  auto alloc = [&](size_t bytes) {
    char* r = p;
    p += (bytes + 255) & ~(size_t)255;
    return r;
  };
  float* xz = (float*)alloc(2048ull * 3072 * 4);     // in_proj out (xin | z)
  float* xinc = (float*)alloc(2048ull * 1536 * 4);   // conv+silu fp32
  u16* xihl = (u16*)alloc(2048ull * 3072 * 2);       // conv+silu hi|lo concat
  float* dbc = (float*)alloc(2048ull * 80 * 4);      // x_proj out
  float* delta = (float*)alloc(2048ull * 1536 * 4);  // softplus(dt_proj)
  u16* ymhl = (u16*)alloc(2048ull * 3072 * 2);       // gated scan out hi|lo
  float* gout = (float*)alloc(2048ull * 768 * 4);    // out_proj (pre-LN)
  u16* xhl = (u16*)alloc(2048ull * 1536 * 2);        // layer input hi|lo
  u16* w_in_h = (u16*)alloc(2ull * 3072 * 768 * 2);  // bf16 weights (plain)
  u16* w_xp_h = (u16*)alloc(2ull * 80 * 1536 * 2);
  u16* w_out_h = (u16*)alloc(2ull * 768 * 1536 * 2);
  u16* w_head_h = (u16*)alloc(32000ull * 768 * 2);
  float* dtwT = (float*)alloc(2ull * 48 * 1536 * 4);           // transposed dt_w
  float* chP = (float*)alloc(2ull * SCAN_NC * 1536 * 16 * 4);  // chunk prod(dA)
  float* chQ = (float*)alloc(2ull * SCAN_NC * 1536 * 16 * 4);  // chunk local h
  float* hst = (float*)alloc(2ull * SCAN_NC * 1536 * 16 * 4);  // chunk h_start

  // weight pre-pass
  k_cvt_all<<<2048, 256, 0, stream>>>(in_w, w_in_h, 2 * 3072 * 768,
                                      xp_w, w_xp_h, 2 * 80 * 1536,
                                      out_w, w_out_h, 2 * 768 * 1536,
                                      head_w, w_head_h, 32000 * 768);
  k_dtt<<<576, 256, 0, stream>>>(dt_w, dtwT);

  k_embed<<<2048, 256, 0, stream>>>(tokens, embed, xhl);

  for (int l = 0; l < 2; ++l) {
    // in_proj: M=2048 N=3072 K'=1536 (K0=768) -> gemm4, grid 16*24=384
    gemm4<false><<<384, 256, 0, stream>>>(
        xhl, w_in_h + (size_t)l * 2359296, xz, nullptr, 2048, 3072, 1536, 768, 3072);

    k_conv<<<12288, 256, 0, stream>>>(xz, conv_w + l * 6144, conv_b + l * 1536, xinc, xihl);

    // x_proj: N=80 K'=3072 (K0=1536) -> split-K (12 chunks of 256) atomic
    k_zero<<<640, 256, 0, stream>>>(dbc, 2048 * 80);
    gemm_bt<false, true><<<dim3(1, 16, 12), 256, 0, stream>>>(
        xihl, w_xp_h + (size_t)l * 122880, dbc, nullptr, 2048, 80, 3072, 1536, 80, 256);

    k_dt<<<2048, 256, 0, stream>>>(dbc, dtwT + (size_t)l * 73728, dt_b + l * 1536, delta);

    k_scan1<<<dim3(96, 2, SCAN_NC), 256, 0, stream>>>(
        delta, xinc, dbc, A_log + l * 24576, chP, chQ);
    k_scan_fix<<<dim3(96, 2), 256, 0, stream>>>(chP, chQ, hst);
    k_scan2<<<dim3(96, 2, SCAN_NC), 256, 0, stream>>>(
        delta, xinc, dbc, xz, A_log + l * 24576, D_par + l * 1536, hst, ymhl);

    // out_proj: N=768 K'=3072 (K0=1536) -> split-K (8 chunks of 384) atomic
    k_zero<<<6144, 256, 0, stream>>>(gout, 2048 * 768);
    gemm_bt<false, true><<<dim3(6, 16, 8), 256, 0, stream>>>(
        ymhl, w_out_h + (size_t)l * 1179648, gout, nullptr, 2048, 768, 3072, 1536, 768, 384);

    k_ln<<<2048, 256, 0, stream>>>(gout, ln_w + l * 768, ln_b + l * 768, xhl);
  }

  // head: M=2048 N=32000 K'=1536 (K0=768) -> gemm4, grid 16*250=4000
  gemm4<true><<<4000, 256, 0, stream>>>(
      xhl, w_head_h, (float*)d_out, head_b, 2048, 32000, 1536, 768, 32000);
}